// Round 4
// baseline (129.723 us; speedup 1.0000x reference)
//
#include <hip/hip_runtime.h>
#include <cstdint>
#include <cstddef>

typedef unsigned long long u64;

// Problem constants (N,P,T,H,W) = (8,32,16,384,384)
constexpr int N_  = 8;
constexpr int P_  = 32;
constexpr int T_  = 16;
constexpr int HW  = 384 * 384;        // 147456 pixels per mask
constexpr int WORDS = HW / 64;        // 2304 u64 words per mask
constexpr int GPN = HW / 256;         // 576 256-pixel groups per image
constexpr int M_  = P_ + T_;          // 48 masks per image
constexpr int CHUNK = 4;              // pixel-groups per block
constexpr int BPN = GPN / CHUNK;      // 144 blocks per image
constexpr int LSTR = 18;              // LDS row stride in u64 (16B-aligned, de-banked)

// ---------------------------------------------------------------------------
// Fused pack + pairwise-intersection + areas.
// One block = CHUNK pixel-groups (256 px each) of one image.
// Phase A (no syncs): wave w handles masks m = w*12..w*12+11. Per group:
//   explicit 12-wide float4 preload (keeps 12 loads in flight per wave),
//   then ballots -> 4 bit-words/mask -> LDS; per-mask area in registers.
// One __syncthreads, then:
// Phase B: thread (p = tid>>3, tpair = tid&7) accumulates
//   popcount(pred[p] & true[t]) for t = 2*tpair(+1) over all CHUNK groups,
//   and a coalesced store pass writes packed pred words (128 B/mask runs).
// Block-end: one atomicAdd per accumulator (exact ints -> deterministic).
// ---------------------------------------------------------------------------
__global__ __launch_bounds__(256)
void fused_pack_inter(const float* __restrict__ gp, const float* __restrict__ gt,
                      u64* __restrict__ pp, int* __restrict__ inter,
                      int* __restrict__ area) {
    __shared__ __align__(16) u64 wlds[M_][LSTR];   // [mask][c*4+j], 6912 B

    const int tid  = threadIdx.x;
    const int lane = tid & 63;
    const int wv   = tid >> 6;
    const int n    = blockIdx.x / BPN;
    const int g0   = (blockIdx.x - n * BPN) * CHUNK;

    // Per-wave mask base pointers (static after unroll -> registers)
    const float* base[12];
    #pragma unroll
    for (int k = 0; k < 12; ++k) {
        const int m = wv * 12 + k;
        base[k] = (m < P_) ? gp + (size_t)(n * P_ + m) * HW
                           : gt + (size_t)(n * T_ + (m - P_)) * HW;
    }

    int areaAcc[12] = {};

    #pragma unroll
    for (int c = 0; c < CHUNK; ++c) {
        const int g = g0 + c;
        float4 v[12];
        #pragma unroll
        for (int k = 0; k < 12; ++k)
            v[k] = reinterpret_cast<const float4*>(base[k] + (size_t)g * 256)[lane];
        #pragma unroll
        for (int k = 0; k < 12; ++k) {
            u64 b0 = __ballot(v[k].x != 0.0f);
            u64 b1 = __ballot(v[k].y != 0.0f);
            u64 b2 = __ballot(v[k].z != 0.0f);
            u64 b3 = __ballot(v[k].w != 0.0f);
            areaAcc[k] += __popcll(b0) + __popcll(b1) + __popcll(b2) + __popcll(b3);
            if (lane == 0) {
                ulonglong2 w01, w23;
                w01.x = b0; w01.y = b1; w23.x = b2; w23.y = b3;
                *reinterpret_cast<ulonglong2*>(&wlds[wv * 12 + k][c * 4])     = w01;
                *reinterpret_cast<ulonglong2*>(&wlds[wv * 12 + k][c * 4 + 2]) = w23;
            }
        }
    }

    __syncthreads();   // the only barrier in this kernel

    // Coalesced packed-pred store: thread (m = tid>>3, j = tid&7) stores
    // 16 B; per mask a contiguous 128 B run (CHUNK*4 words).
    {
        const int m = tid >> 3, j = tid & 7;
        ulonglong2 w;
        w.x = wlds[m][2 * j];
        w.y = wlds[m][2 * j + 1];
        u64* dst = pp + (size_t)(n * P_ + m) * WORDS + (size_t)g0 * 4 + 2 * j;
        if (m < P_) *reinterpret_cast<ulonglong2*>(dst) = w;
    }

    // Phase B: pairwise AND-popcounts from LDS (broadcast reads, de-banked rows)
    const int p  = tid >> 3;
    const int t0 = (tid & 7) * 2;
    const int t1 = t0 + 1;
    int acc0 = 0, acc1 = 0;
    #pragma unroll
    for (int c = 0; c < CHUNK; ++c) {
        ulonglong2 a01 = *reinterpret_cast<const ulonglong2*>(&wlds[p][c * 4]);
        ulonglong2 a23 = *reinterpret_cast<const ulonglong2*>(&wlds[p][c * 4 + 2]);
        ulonglong2 b01 = *reinterpret_cast<const ulonglong2*>(&wlds[P_ + t0][c * 4]);
        ulonglong2 b23 = *reinterpret_cast<const ulonglong2*>(&wlds[P_ + t0][c * 4 + 2]);
        ulonglong2 c01 = *reinterpret_cast<const ulonglong2*>(&wlds[P_ + t1][c * 4]);
        ulonglong2 c23 = *reinterpret_cast<const ulonglong2*>(&wlds[P_ + t1][c * 4 + 2]);
        acc0 += __popcll(a01.x & b01.x) + __popcll(a01.y & b01.y)
              + __popcll(a23.x & b23.x) + __popcll(a23.y & b23.y);
        acc1 += __popcll(a01.x & c01.x) + __popcll(a01.y & c01.y)
              + __popcll(a23.x & c23.x) + __popcll(a23.y & c23.y);
    }
    atomicAdd(&inter[(n * P_ + p) * T_ + t0], acc0);
    atomicAdd(&inter[(n * P_ + p) * T_ + t1], acc1);

    if (lane == 0) {
        #pragma unroll
        for (int k = 0; k < 12; ++k)
            atomicAdd(&area[n * M_ + wv * 12 + k], areaAcc[k]);
    }
}

// ---------------------------------------------------------------------------
// Per-pixel score with iou_max recomputed per block from the exact int
// tables. One block = 4 pixel-groups (1024 px) of one image; packed-pred
// words staged to LDS with coalesced loads, consumed as wave-uniform
// broadcast reads.
// ---------------------------------------------------------------------------
__global__ __launch_bounds__(256)
void score_kernel(const u64* __restrict__ pm,
                  const int* __restrict__ inter,
                  const int* __restrict__ area,
                  float* __restrict__ out) {
    __shared__ u64   wlds[P_][16];
    __shared__ float iou[P_];

    const int tid  = threadIdx.x;
    const int lane = tid & 63;
    const int wv   = tid >> 6;
    const int gblk = blockIdx.x * 4;
    const int n    = gblk / GPN;
    const int gl0  = gblk - n * GPN;

    {
        int p = tid >> 3, k = tid & 7;
        const u64* s = pm + (size_t)(n * P_ + p) * WORDS + (size_t)gl0 * 4 + 2 * k;
        *reinterpret_cast<ulonglong2*>(&wlds[p][2 * k]) =
            *reinterpret_cast<const ulonglong2*>(s);
    }

    if (tid < P_) {
        float ap = (float)area[n * M_ + tid];
        float best = 0.0f;
        #pragma unroll
        for (int t = 0; t < T_; ++t) {
            float it = (float)inter[(n * P_ + tid) * T_ + t];
            float u  = ap + (float)area[n * M_ + P_ + t] - it;
            best = fmaxf(best, (u > 0.0f) ? it / u : 0.0f);
        }
        iou[tid] = best;
    }
    __syncthreads();

    float num0 = 0.f, num1 = 0.f, num2 = 0.f, num3 = 0.f;
    int   den0 = 0, den1 = 0, den2 = 0, den3 = 0;
    #pragma unroll
    for (int p = 0; p < P_; ++p) {
        float w8 = iou[p];
        u64 w0 = wlds[p][wv * 4 + 0];   // uniform addr per wave -> broadcast
        u64 w1 = wlds[p][wv * 4 + 1];
        u64 w2 = wlds[p][wv * 4 + 2];
        u64 w3 = wlds[p][wv * 4 + 3];
        unsigned b0 = (unsigned)(w0 >> lane) & 1u;
        unsigned b1 = (unsigned)(w1 >> lane) & 1u;
        unsigned b2 = (unsigned)(w2 >> lane) & 1u;
        unsigned b3 = (unsigned)(w3 >> lane) & 1u;
        num0 += b0 ? w8 : 0.0f;  den0 += b0;
        num1 += b1 ? w8 : 0.0f;  den1 += b1;
        num2 += b2 ? w8 : 0.0f;  den2 += b2;
        num3 += b3 ? w8 : 0.0f;  den3 += b3;
    }

    float4 o;
    o.x = den0 ? num0 / (float)den0 : 0.0f;
    o.y = den1 ? num1 / (float)den1 : 0.0f;
    o.z = den2 ? num2 / (float)den2 : 0.0f;
    o.w = den3 ? num3 / (float)den3 : 0.0f;
    reinterpret_cast<float4*>(out)[(size_t)(gblk + wv) * 64 + lane] = o;
}

extern "C" void kernel_launch(void* const* d_in, const int* in_sizes, int n_in,
                              void* d_out, int out_size, void* d_ws, size_t ws_size,
                              hipStream_t stream) {
    const float* gp = (const float*)d_in[0];   // (N,P,H,W)
    const float* gt = (const float*)d_in[1];   // (N,T,H,W)
    float* out = (float*)d_out;                // (N,H,W)

    char* ws = (char*)d_ws;
    int* inter = (int*)ws;                         // 8*32*16*4 = 16384 B
    int* area  = (int*)(ws + 16384);               // 8*48*4   = 1536 B
    u64* packed_p = (u64*)(ws + 16384 + 1536);     // 17920 % 16 == 0; 4.72 MB

    // Atomic accumulators must start at zero every call (harness poisons ws
    // once and never re-poisons between graph replays).
    hipMemsetAsync(ws, 0, 16384 + 1536, stream);

    hipLaunchKernelGGL(fused_pack_inter, dim3(N_ * BPN), dim3(256), 0, stream,
                       gp, gt, packed_p, inter, area);
    hipLaunchKernelGGL(score_kernel, dim3(N_ * GPN / 4), dim3(256), 0, stream,
                       packed_p, inter, area, out);
}

// Round 5
// 73.210 us; speedup vs baseline: 1.7719x; 1.7719x over previous
//
#include <hip/hip_runtime.h>
#include <cstdint>
#include <cstddef>

typedef unsigned long long u64;

// Problem constants (N,P,T,H,W) = (8,32,16,384,384)
constexpr int N_  = 8;
constexpr int P_  = 32;
constexpr int T_  = 16;
constexpr int HW  = 384 * 384;        // 147456 pixels per mask
constexpr int WORDS = HW / 64;        // 2304 u64 words per mask
constexpr int GPN = HW / 256;         // 576 256-pixel groups per image
constexpr int PG  = N_ * P_ * HW / 256;   // 147456 pred groups
constexpr int TG  = N_ * T_ * HW / 256;   //  73728 true groups

// ---------------------------------------------------------------------------
// Pack BOTH inputs into bits, one launch. One wave = one 256-pixel group per
// grid-stride step: lane l loads float4 at pixel g*256+4l; bit layout:
// word[g*4+j] bit l = pixel (g*256 + 4l + j). Latency hidden by TLP (8192
// independent waves), which round 2 proved reaches streaming BW.
// ---------------------------------------------------------------------------
__global__ __launch_bounds__(256)
void pack_all(const float* __restrict__ gp, const float* __restrict__ gt,
              u64* __restrict__ pp, u64* __restrict__ pt) {
    int wave   = (blockIdx.x * blockDim.x + threadIdx.x) >> 6;
    int lane   = threadIdx.x & 63;
    int nwaves = (gridDim.x * blockDim.x) >> 6;
    for (int g = wave; g < PG + TG; g += nwaves) {
        const float4* src;
        u64* dst;
        if (g < PG) { src = reinterpret_cast<const float4*>(gp) + (size_t)g * 64;
                      dst = pp + (size_t)g * 4; }
        else        { src = reinterpret_cast<const float4*>(gt) + (size_t)(g - PG) * 64;
                      dst = pt + (size_t)(g - PG) * 4; }
        float4 v = src[lane];
        u64 b0 = __ballot(v.x != 0.0f);
        u64 b1 = __ballot(v.y != 0.0f);
        u64 b2 = __ballot(v.z != 0.0f);
        u64 b3 = __ballot(v.w != 0.0f);
        if (lane == 0) { dst[0] = b0; dst[1] = b1; dst[2] = b2; dst[3] = b3; }
    }
}

// ---------------------------------------------------------------------------
// iou_max per (n,p), one 256-thread block each. Pred words live in registers
// (a[9]); the t*k loop is fully unrolled straight-line code (no branches, no
// exec-mask writes) over coalesced L2/L3-hot loads, accumulating all 16
// intersections + 16 true-areas + pred-area in registers. One batched
// 33-value reduction (6 shfl steps each, one syncthreads) replaces 16
// serialized block-reduces. Block then computes iou_max directly.
// ---------------------------------------------------------------------------
__global__ __launch_bounds__(256)
void ioumax_kernel(const u64* __restrict__ pp, const u64* __restrict__ pt,
                   float* __restrict__ ioumax) {
    __shared__ int   red[4][33];
    __shared__ int   tot[33];
    __shared__ float shiou[T_];

    const int np  = blockIdx.x;          // n*P + p
    const int n   = np >> 5;
    const int tid = threadIdx.x;
    const int lane = tid & 63;
    const int wv   = tid >> 6;

    const u64* pw = pp + (size_t)np * WORDS;
    u64 a[9];
    #pragma unroll
    for (int k = 0; k < 9; ++k) a[k] = pw[tid + 256 * k];

    int vals[33];
    {
        int ap = 0;
        #pragma unroll
        for (int k = 0; k < 9; ++k) ap += __popcll(a[k]);
        vals[0] = ap;
    }
    #pragma unroll
    for (int t = 0; t < T_; ++t) {
        const u64* tw = pt + (size_t)(n * T_ + t) * WORDS;
        int s = 0, st = 0;
        #pragma unroll
        for (int k = 0; k < 9; ++k) {
            u64 w = tw[tid + 256 * k];
            s  += __popcll(a[k] & w);
            st += __popcll(w);
        }
        vals[1 + t]       = s;
        vals[1 + T_ + t]  = st;
    }

    // Batched wave reduce (result in lane 0 of each wave), then cross-wave.
    #pragma unroll
    for (int i = 0; i < 33; ++i) {
        int v = vals[i];
        v += __shfl_down(v, 32);
        v += __shfl_down(v, 16);
        v += __shfl_down(v, 8);
        v += __shfl_down(v, 4);
        v += __shfl_down(v, 2);
        v += __shfl_down(v, 1);
        if (lane == 0) red[wv][i] = v;
    }
    __syncthreads();
    if (tid < 33) tot[tid] = red[0][tid] + red[1][tid] + red[2][tid] + red[3][tid];
    __syncthreads();
    if (tid < T_) {
        float it = (float)tot[1 + tid];
        float u  = (float)tot[0] + (float)tot[1 + T_ + tid] - it;
        shiou[tid] = (u > 0.0f) ? it / u : 0.0f;
    }
    __syncthreads();
    if (tid == 0) {
        float best = 0.0f;
        #pragma unroll
        for (int t = 0; t < T_; ++t) best = fmaxf(best, shiou[t]);
        ioumax[np] = best;
    }
}

// ---------------------------------------------------------------------------
// Per-pixel score. One block = 4 pixel-groups (1024 px) of one image;
// packed-pred words staged to LDS with coalesced loads, consumed as
// wave-uniform broadcast reads.
// ---------------------------------------------------------------------------
__global__ __launch_bounds__(256)
void score_kernel(const u64* __restrict__ pm,
                  const float* __restrict__ ioumax,
                  float* __restrict__ out) {
    __shared__ u64   wlds[P_][16];
    __shared__ float iou[P_];

    const int tid  = threadIdx.x;
    const int lane = tid & 63;
    const int wv   = tid >> 6;
    const int gblk = blockIdx.x * 4;
    const int n    = gblk / GPN;
    const int gl0  = gblk - n * GPN;

    {
        int p = tid >> 3, k = tid & 7;
        const u64* s = pm + (size_t)(n * P_ + p) * WORDS + (size_t)gl0 * 4 + 2 * k;
        *reinterpret_cast<ulonglong2*>(&wlds[p][2 * k]) =
            *reinterpret_cast<const ulonglong2*>(s);
    }
    if (tid < P_) iou[tid] = ioumax[n * P_ + tid];
    __syncthreads();

    float num0 = 0.f, num1 = 0.f, num2 = 0.f, num3 = 0.f;
    int   den0 = 0, den1 = 0, den2 = 0, den3 = 0;
    #pragma unroll
    for (int p = 0; p < P_; ++p) {
        float w8 = iou[p];
        u64 w0 = wlds[p][wv * 4 + 0];   // uniform addr per wave -> broadcast
        u64 w1 = wlds[p][wv * 4 + 1];
        u64 w2 = wlds[p][wv * 4 + 2];
        u64 w3 = wlds[p][wv * 4 + 3];
        unsigned b0 = (unsigned)(w0 >> lane) & 1u;
        unsigned b1 = (unsigned)(w1 >> lane) & 1u;
        unsigned b2 = (unsigned)(w2 >> lane) & 1u;
        unsigned b3 = (unsigned)(w3 >> lane) & 1u;
        num0 += b0 ? w8 : 0.0f;  den0 += b0;
        num1 += b1 ? w8 : 0.0f;  den1 += b1;
        num2 += b2 ? w8 : 0.0f;  den2 += b2;
        num3 += b3 ? w8 : 0.0f;  den3 += b3;
    }

    float4 o;
    o.x = den0 ? num0 / (float)den0 : 0.0f;
    o.y = den1 ? num1 / (float)den1 : 0.0f;
    o.z = den2 ? num2 / (float)den2 : 0.0f;
    o.w = den3 ? num3 / (float)den3 : 0.0f;
    reinterpret_cast<float4*>(out)[(size_t)(gblk + wv) * 64 + lane] = o;
}

extern "C" void kernel_launch(void* const* d_in, const int* in_sizes, int n_in,
                              void* d_out, int out_size, void* d_ws, size_t ws_size,
                              hipStream_t stream) {
    const float* gp = (const float*)d_in[0];   // (N,P,H,W)
    const float* gt = (const float*)d_in[1];   // (N,T,H,W)
    float* out = (float*)d_out;                // (N,H,W)

    char* ws = (char*)d_ws;
    u64* packed_p = (u64*)ws;                                       // 4,718,592 B
    u64* packed_t = (u64*)(ws + (size_t)N_ * P_ * WORDS * 8);       // 2,359,296 B
    float* ioumax = (float*)(ws + (size_t)(N_ * P_ + N_ * T_) * WORDS * 8);  // 1 KB

    // Every output buffer (packed_p, packed_t, ioumax, out) is fully
    // overwritten each call -> deterministic, no memset needed.
    hipLaunchKernelGGL(pack_all, dim3(2048), dim3(256), 0, stream,
                       gp, gt, packed_p, packed_t);
    hipLaunchKernelGGL(ioumax_kernel, dim3(N_ * P_), dim3(256), 0, stream,
                       packed_p, packed_t, ioumax);
    hipLaunchKernelGGL(score_kernel, dim3(N_ * GPN / 4), dim3(256), 0, stream,
                       packed_p, ioumax, out);
}

// Round 6
// 71.435 us; speedup vs baseline: 1.8160x; 1.0248x over previous
//
#include <hip/hip_runtime.h>
#include <cstdint>
#include <cstddef>

typedef unsigned long long u64;

// Problem constants (N,P,T,H,W) = (8,32,16,384,384)
constexpr int N_  = 8;
constexpr int P_  = 32;
constexpr int T_  = 16;
constexpr int HW  = 384 * 384;        // 147456 pixels per mask
constexpr int WORDS = HW / 64;        // 2304 u64 words per mask
constexpr int GPN = HW / 256;         // 576 256-pixel groups per image
constexpr int PG  = N_ * P_ * HW / 256;   // 147456 pred groups
constexpr int TG  = N_ * T_ * HW / 256;   //  73728 true groups
constexpr int TOTG = PG + TG;             // 221184 groups
constexpr int BATCH = 8;                  // groups per wave-iteration (8 KB in flight)
constexpr int PACK_BLOCKS = 1728;         // 6912 waves * 4 iters * 8 groups = TOTG exactly

// ---------------------------------------------------------------------------
// Pack BOTH inputs into bits (one contiguous packed buffer: pred then true).
// Static exact partition: wave w handles groups [w*32, w*32+32) as 4 batches
// of 8. Per batch: 8 independent float4 loads issued before ANY ballot
// (ballot = v_cmp -> SGPR, no exec-mask write), so 8 loads stay in flight
// per wave (the round-4/5 failure was 1 load in flight). Mask boundaries are
// multiples of 32 groups, so a wave never straddles gp/gt.
// Bit layout: word[g*4+j] bit l = pixel (g*256 + 4l + j).
// ---------------------------------------------------------------------------
__global__ __launch_bounds__(256)
void pack_all(const float* __restrict__ gp, const float* __restrict__ gt,
              u64* __restrict__ pk) {
    const int lane = threadIdx.x & 63;
    const int wave = blockIdx.x * 4 + (threadIdx.x >> 6);

    #pragma unroll
    for (int it = 0; it < 4; ++it) {
        const int g0 = (wave * 4 + it) * BATCH;   // first group of this batch
        const float4* src = (g0 < PG)
            ? reinterpret_cast<const float4*>(gp) + (size_t)g0 * 64
            : reinterpret_cast<const float4*>(gt) + (size_t)(g0 - PG) * 64;

        float4 v[BATCH];
        #pragma unroll
        for (int i = 0; i < BATCH; ++i) v[i] = src[(size_t)i * 64 + lane];

        u64 w[BATCH][4];
        #pragma unroll
        for (int i = 0; i < BATCH; ++i) {
            w[i][0] = __ballot(v[i].x != 0.0f);
            w[i][1] = __ballot(v[i].y != 0.0f);
            w[i][2] = __ballot(v[i].z != 0.0f);
            w[i][3] = __ballot(v[i].w != 0.0f);
        }

        if (lane == 0) {
            ulonglong2* dst = reinterpret_cast<ulonglong2*>(pk + (size_t)g0 * 4);
            #pragma unroll
            for (int i = 0; i < BATCH; ++i) {
                ulonglong2 lo, hi;
                lo.x = w[i][0]; lo.y = w[i][1];
                hi.x = w[i][2]; hi.y = w[i][3];
                dst[2 * i]     = lo;
                dst[2 * i + 1] = hi;
            }
        }
    }
}

// ---------------------------------------------------------------------------
// iou_max per (n,p), one 256-thread block each. Pred words in registers
// (a[9]). Loop order k-outer / t-inner: each k step issues 16 INDEPENDENT
// true-word loads (vs 16 serialized 9-load batches before), hiding L2/L3
// latency. All 33 partial sums (area_p, 16 inter, 16 area_t) live in
// registers until one batched shuffle reduction.
// ---------------------------------------------------------------------------
__global__ __launch_bounds__(256)
void ioumax_kernel(const u64* __restrict__ pp, const u64* __restrict__ pt,
                   float* __restrict__ ioumax) {
    __shared__ int   red[4][33];
    __shared__ int   tot[33];
    __shared__ float shiou[T_];

    const int np  = blockIdx.x;          // n*P + p
    const int n   = np >> 5;
    const int tid = threadIdx.x;
    const int lane = tid & 63;
    const int wv   = tid >> 6;

    const u64* pw = pp + (size_t)np * WORDS;
    const u64* tb = pt + (size_t)n * T_ * WORDS;   // image-n true base

    u64 a[9];
    #pragma unroll
    for (int k = 0; k < 9; ++k) a[k] = pw[tid + 256 * k];

    int ap = 0;
    int inter[T_] = {};
    int areat[T_] = {};
    for (int k = 0; k < 9; ++k) {
        u64 tw[T_];
        #pragma unroll
        for (int t = 0; t < T_; ++t) tw[t] = tb[(size_t)t * WORDS + tid + 256 * k];
        ap += __popcll(a[k]);
        #pragma unroll
        for (int t = 0; t < T_; ++t) {
            inter[t] += __popcll(a[k] & tw[t]);
            areat[t] += __popcll(tw[t]);
        }
    }

    int vals[33];
    vals[0] = ap;
    #pragma unroll
    for (int t = 0; t < T_; ++t) { vals[1 + t] = inter[t]; vals[1 + T_ + t] = areat[t]; }

    #pragma unroll
    for (int i = 0; i < 33; ++i) {
        int v = vals[i];
        v += __shfl_down(v, 32);
        v += __shfl_down(v, 16);
        v += __shfl_down(v, 8);
        v += __shfl_down(v, 4);
        v += __shfl_down(v, 2);
        v += __shfl_down(v, 1);
        if (lane == 0) red[wv][i] = v;
    }
    __syncthreads();
    if (tid < 33) tot[tid] = red[0][tid] + red[1][tid] + red[2][tid] + red[3][tid];
    __syncthreads();
    if (tid < T_) {
        float it = (float)tot[1 + tid];
        float u  = (float)tot[0] + (float)tot[1 + T_ + tid] - it;
        shiou[tid] = (u > 0.0f) ? it / u : 0.0f;
    }
    __syncthreads();
    if (tid == 0) {
        float best = 0.0f;
        #pragma unroll
        for (int t = 0; t < T_; ++t) best = fmaxf(best, shiou[t]);
        ioumax[np] = best;
    }
}

// ---------------------------------------------------------------------------
// Per-pixel score. One block = 4 pixel-groups (1024 px) of one image;
// packed-pred words staged to LDS with coalesced loads, consumed as
// wave-uniform broadcast reads.
// ---------------------------------------------------------------------------
__global__ __launch_bounds__(256)
void score_kernel(const u64* __restrict__ pm,
                  const float* __restrict__ ioumax,
                  float* __restrict__ out) {
    __shared__ u64   wlds[P_][16];
    __shared__ float iou[P_];

    const int tid  = threadIdx.x;
    const int lane = tid & 63;
    const int wv   = tid >> 6;
    const int gblk = blockIdx.x * 4;
    const int n    = gblk / GPN;
    const int gl0  = gblk - n * GPN;

    {
        int p = tid >> 3, k = tid & 7;
        const u64* s = pm + (size_t)(n * P_ + p) * WORDS + (size_t)gl0 * 4 + 2 * k;
        *reinterpret_cast<ulonglong2*>(&wlds[p][2 * k]) =
            *reinterpret_cast<const ulonglong2*>(s);
    }
    if (tid < P_) iou[tid] = ioumax[n * P_ + tid];
    __syncthreads();

    float num0 = 0.f, num1 = 0.f, num2 = 0.f, num3 = 0.f;
    int   den0 = 0, den1 = 0, den2 = 0, den3 = 0;
    #pragma unroll
    for (int p = 0; p < P_; ++p) {
        float w8 = iou[p];
        u64 w0 = wlds[p][wv * 4 + 0];   // uniform addr per wave -> broadcast
        u64 w1 = wlds[p][wv * 4 + 1];
        u64 w2 = wlds[p][wv * 4 + 2];
        u64 w3 = wlds[p][wv * 4 + 3];
        unsigned b0 = (unsigned)(w0 >> lane) & 1u;
        unsigned b1 = (unsigned)(w1 >> lane) & 1u;
        unsigned b2 = (unsigned)(w2 >> lane) & 1u;
        unsigned b3 = (unsigned)(w3 >> lane) & 1u;
        num0 += b0 ? w8 : 0.0f;  den0 += b0;
        num1 += b1 ? w8 : 0.0f;  den1 += b1;
        num2 += b2 ? w8 : 0.0f;  den2 += b2;
        num3 += b3 ? w8 : 0.0f;  den3 += b3;
    }

    float4 o;
    o.x = den0 ? num0 / (float)den0 : 0.0f;
    o.y = den1 ? num1 / (float)den1 : 0.0f;
    o.z = den2 ? num2 / (float)den2 : 0.0f;
    o.w = den3 ? num3 / (float)den3 : 0.0f;
    reinterpret_cast<float4*>(out)[(size_t)(gblk + wv) * 64 + lane] = o;
}

extern "C" void kernel_launch(void* const* d_in, const int* in_sizes, int n_in,
                              void* d_out, int out_size, void* d_ws, size_t ws_size,
                              hipStream_t stream) {
    const float* gp = (const float*)d_in[0];   // (N,P,H,W)
    const float* gt = (const float*)d_in[1];   // (N,T,H,W)
    float* out = (float*)d_out;                // (N,H,W)

    char* ws = (char*)d_ws;
    u64* packed   = (u64*)ws;                  // pred (4.72 MB) then true (2.36 MB)
    u64* packed_p = packed;
    u64* packed_t = packed + (size_t)PG * 4;
    float* ioumax = (float*)(ws + (size_t)TOTG * 4 * 8);   // 1 KB

    // Every output buffer (packed, ioumax, out) is fully overwritten each
    // call -> deterministic, no memset needed.
    hipLaunchKernelGGL(pack_all, dim3(PACK_BLOCKS), dim3(256), 0, stream,
                       gp, gt, packed);
    hipLaunchKernelGGL(ioumax_kernel, dim3(N_ * P_), dim3(256), 0, stream,
                       packed_p, packed_t, ioumax);
    hipLaunchKernelGGL(score_kernel, dim3(N_ * GPN / 4), dim3(256), 0, stream,
                       packed_p, ioumax, out);
}